// Round 1
// baseline (118.281 us; speedup 1.0000x reference)
//
#include <hip/hip_runtime.h>
#include <hip/hip_bf16.h>

// BinaryConv: BN(train) -> sign -> 3x3 conv with sign(W), via XNOR-popcount.
// x: (32,256,32,32) f32, gamma/beta: (256,), W: (256,256,3,3) f32 OIHW
// out: (32,256,32,32) f32

#define NIMG 32
#define C    256
#define K    256
#define HH   32
#define WW   32

// ---------------- Kernel 1: per-channel stats -> threshold t_c, flip_c -------
__global__ __launch_bounds__(256) void k_stats(
    const float* __restrict__ x, const float* __restrict__ gamma,
    const float* __restrict__ beta, float* __restrict__ t_out,
    unsigned* __restrict__ flip_out) {
  int c = blockIdx.x;
  int tid = threadIdx.x;
  double s = 0.0, sq = 0.0;
  const float* xc = x + (size_t)c * 1024;
  for (int n = 0; n < NIMG; ++n) {
    const float* p = xc + (size_t)n * (C * 1024);
    for (int i = tid; i < 1024; i += 256) {
      float v = p[i];
      s += (double)v;
      sq += (double)v * (double)v;
    }
  }
  // wave reduce (64 lanes)
  for (int o = 32; o > 0; o >>= 1) {
    s += __shfl_down(s, o);
    sq += __shfl_down(sq, o);
  }
  __shared__ double ls[4], lq[4];
  if ((tid & 63) == 0) { ls[tid >> 6] = s; lq[tid >> 6] = sq; }
  __syncthreads();
  if (tid == 0) {
    double S = ls[0] + ls[1] + ls[2] + ls[3];
    double Q = lq[0] + lq[1] + lq[2] + lq[3];
    const double N = 32768.0;
    double mean = S / N;
    double var = Q / N - mean * mean;
    double rs = 1.0 / sqrt(var + 1e-5);
    double g = (double)gamma[c];
    double b = (double)beta[c];
    float t;
    unsigned flip;
    if (g == 0.0) {
      // xn == beta everywhere; a = sign(beta): bit = (beta > 0) for all x
      t = (b > 0.0) ? -3.0e38f : 3.0e38f;  // x > t always / never
      flip = 0u;
    } else {
      double tt = mean - b / (rs * g);
      t = (float)tt;
      flip = (g < 0.0) ? 1u : 0u;
    }
    t_out[c] = t;
    flip_out[c] = flip;
  }
}

// ---------------- Kernel 2: pack sign(W) bits: wp[(k*9+t)*8 + j] -------------
__global__ __launch_bounds__(256) void k_packw(const float* __restrict__ W,
                                               unsigned* __restrict__ wp) {
  int idx = blockIdx.x * 256 + threadIdx.x;  // 0..2303  (k, tap)
  if (idx >= K * 9) return;
  int k = idx / 9, t = idx % 9;
  unsigned w[8] = {0, 0, 0, 0, 0, 0, 0, 0};
  const float* base = W + (size_t)k * (C * 9) + t;
  #pragma unroll 8
  for (int c = 0; c < C; ++c) {
    unsigned bit = (base[(size_t)c * 9] > 0.0f) ? 1u : 0u;
    w[c >> 5] |= bit << (c & 31);
  }
  unsigned* o = wp + (size_t)idx * 8;
  #pragma unroll
  for (int j = 0; j < 8; ++j) o[j] = w[j];
}

// ------------- Kernel 3: binarize + bit-pack activations (NHW, C-bits) -------
// ap[((n*32+y)*32+x)*8 + j], bit c of word c>>5 set iff a(n,c,y,x) == +1
__global__ __launch_bounds__(256) void k_packa(
    const float* __restrict__ x, const float* __restrict__ t,
    const unsigned* __restrict__ flip, unsigned* __restrict__ ap) {
  int n = blockIdx.y;
  int p0 = blockIdx.x * 64;          // 64 pixels per block
  int pix = threadIdx.x & 63;
  int q = threadIdx.x >> 6;          // channel quarter: c in [q*64, q*64+64)
  unsigned w0 = 0, w1 = 0;
  const float* xb = x + (size_t)n * (C * 1024) + p0 + pix;
  #pragma unroll
  for (int i = 0; i < 64; ++i) {
    int c = q * 64 + i;
    float tv = t[c];
    unsigned fl = flip[c];
    float v = xb[(size_t)c * 1024];
    unsigned bit = ((v > tv) ? 1u : 0u) ^ fl;
    if (i < 32) w0 |= bit << i;
    else        w1 |= bit << (i - 32);
  }
  uint2 st; st.x = w0; st.y = w1;
  *(uint2*)(ap + ((size_t)n * 1024 + p0 + pix) * 8 + q * 2) = st;
}

// ---------------- Kernel 4: XNOR-popcount conv ------------------------------
// grid (kchunk=8, ystrip=4, n=32), block 256 (4 waves; wave = 2 rows x 32 cols)
__global__ __launch_bounds__(256) void k_conv(
    const unsigned* __restrict__ ap, const unsigned* __restrict__ wp,
    float* __restrict__ out) {
  int n = blockIdx.z;
  int ystrip = blockIdx.y;
  int kc = blockIdx.x;
  int tid = threadIdx.x;
  int lane = tid & 63;
  int wave = tid >> 6;
  int y = ystrip * 8 + wave * 2 + (lane >> 5);
  int xx = lane & 31;

  uint4 a0[9], a1[9];
  int m[9];
  #pragma unroll
  for (int t = 0; t < 9; ++t) {
    int dy = t / 3 - 1, dx = t % 3 - 1;
    int cy = y + dy, cx = xx + dx;
    bool valid = (cy >= 0) & (cy < 32) & (cx >= 0) & (cx < 32);
    m[t] = valid ? -1 : 0;
    int ry = min(max(cy, 0), 31), rx = min(max(cx, 0), 31);
    const uint4* pa = (const uint4*)(ap + (((size_t)n * 32 + ry) * 32 + rx) * 8);
    a0[t] = pa[0];
    a1[t] = pa[1];
  }

  float* ob = out + (size_t)n * (K * 1024) + (size_t)y * 32 + xx;
  for (int kk = 0; kk < 32; ++kk) {
    int k = kc * 32 + kk;
    const uint4* wq = (const uint4*)(wp + (size_t)k * 72);
    int total = 0;
    #pragma unroll
    for (int t = 0; t < 9; ++t) {
      uint4 wa = wq[t * 2];
      uint4 wb = wq[t * 2 + 1];
      int p = -128;
      p += __popc(a0[t].x ^ wa.x);
      p += __popc(a0[t].y ^ wa.y);
      p += __popc(a0[t].z ^ wa.z);
      p += __popc(a0[t].w ^ wa.w);
      p += __popc(a1[t].x ^ wb.x);
      p += __popc(a1[t].y ^ wb.y);
      p += __popc(a1[t].z ^ wb.z);
      p += __popc(a1[t].w ^ wb.w);
      total += p & m[t];
    }
    ob[(size_t)k * 1024] = (float)(-2 * total);
  }
}

extern "C" void kernel_launch(void* const* d_in, const int* in_sizes, int n_in,
                              void* d_out, int out_size, void* d_ws, size_t ws_size,
                              hipStream_t stream) {
  const float* x = (const float*)d_in[0];
  const float* gamma = (const float*)d_in[1];
  const float* beta = (const float*)d_in[2];
  const float* W = (const float*)d_in[3];
  float* out = (float*)d_out;

  char* ws = (char*)d_ws;
  float* t = (float*)ws;                       // 256 floats
  unsigned* flip = (unsigned*)(ws + 1024);     // 256 u32
  unsigned* wp = (unsigned*)(ws + 4096);       // 2304*8 u32 = 72 KB
  unsigned* ap = (unsigned*)(ws + 131072);     // 32768*8 u32 = 1 MB

  k_stats<<<256, 256, 0, stream>>>(x, gamma, beta, t, flip);
  k_packw<<<9, 256, 0, stream>>>(W, wp);
  k_packa<<<dim3(16, 32), 256, 0, stream>>>(x, t, flip, ap);
  k_conv<<<dim3(8, 4, 32), 256, 0, stream>>>(ap, wp, out);
}

// Round 2
// 86.425 us; speedup vs baseline: 1.3686x; 1.3686x over previous
//
#include <hip/hip_runtime.h>
#include <hip/hip_bf16.h>

// BinaryConv: BN(train) -> sign -> 3x3 conv with sign(W), via XNOR-popcount.
// x: (32,256,32,32) f32, gamma/beta: (256,), W: (256,256,3,3) f32 OIHW
// out: (32,256,32,32) f32

#define NIMG 32
#define C    256
#define K    256

// ---------------- Kernel 1a: partial per-channel stats ----------------------
// grid (8 image-groups, 256 channels), block 256. Each block reads 4 images'
// rows of one channel (4 x 4KB contiguous), f64 partial sums.
__global__ __launch_bounds__(256) void k_stats_part(
    const float* __restrict__ x, double2* __restrict__ partials) {
  int grp = blockIdx.x;   // 0..7
  int c = blockIdx.y;     // 0..255
  int tid = threadIdx.x;
  double s = 0.0, sq = 0.0;
  #pragma unroll
  for (int ni = 0; ni < 4; ++ni) {
    int n = grp * 4 + ni;
    const float* p = x + (size_t)n * (C * 1024) + (size_t)c * 1024;
    float4 v = ((const float4*)p)[tid];
    s += (double)v.x + (double)v.y + (double)v.z + (double)v.w;
    sq += (double)v.x * v.x + (double)v.y * v.y
        + (double)v.z * v.z + (double)v.w * v.w;
  }
  for (int o = 32; o > 0; o >>= 1) {
    s += __shfl_down(s, o);
    sq += __shfl_down(sq, o);
  }
  __shared__ double ls[4], lq[4];
  if ((tid & 63) == 0) { ls[tid >> 6] = s; lq[tid >> 6] = sq; }
  __syncthreads();
  if (tid == 0) {
    double2 r;
    r.x = ls[0] + ls[1] + ls[2] + ls[3];
    r.y = lq[0] + lq[1] + lq[2] + lq[3];
    partials[c * 8 + grp] = r;
  }
}

// ---------------- Kernel 1b: fold partials -> threshold t_c, flip_c ---------
__global__ __launch_bounds__(256) void k_stats_final(
    const double2* __restrict__ partials, const float* __restrict__ gamma,
    const float* __restrict__ beta, float* __restrict__ t_out,
    unsigned* __restrict__ flip_out) {
  int c = threadIdx.x;
  double S = 0.0, Q = 0.0;
  #pragma unroll
  for (int g = 0; g < 8; ++g) {          // fixed order -> deterministic
    double2 p = partials[c * 8 + g];
    S += p.x; Q += p.y;
  }
  const double N = 32768.0;
  double mean = S / N;
  double var = Q / N - mean * mean;
  double rs = 1.0 / sqrt(var + 1e-5);
  double g = (double)gamma[c];
  double b = (double)beta[c];
  float t;
  unsigned flip;
  if (g == 0.0) {
    t = (b > 0.0) ? -3.0e38f : 3.0e38f;  // bit = (beta>0) everywhere
    flip = 0u;
  } else {
    t = (float)(mean - b / (rs * g));
    flip = (g < 0.0) ? 1u : 0u;
  }
  t_out[c] = t;
  flip_out[c] = flip;
}

// ---------------- Kernel 2: pack sign(W) bits + zero page -------------------
// wp[(k*9+t)*8 + j]; zp[0..7] = 0 (zero page for invalid taps)
__global__ __launch_bounds__(256) void k_packw(const float* __restrict__ W,
                                               unsigned* __restrict__ wp,
                                               unsigned* __restrict__ zp) {
  int idx = blockIdx.x * 256 + threadIdx.x;  // 0..2303  (k, tap)
  if (blockIdx.x == 0 && threadIdx.x < 8) zp[threadIdx.x] = 0u;
  if (idx >= K * 9) return;
  int k = idx / 9, t = idx % 9;
  unsigned w[8] = {0, 0, 0, 0, 0, 0, 0, 0};
  const float* base = W + (size_t)k * (C * 9) + t;
  #pragma unroll 8
  for (int c = 0; c < C; ++c) {
    unsigned bit = (base[(size_t)c * 9] > 0.0f) ? 1u : 0u;
    w[c >> 5] |= bit << (c & 31);
  }
  unsigned* o = wp + (size_t)idx * 8;
  #pragma unroll
  for (int j = 0; j < 8; ++j) o[j] = w[j];
}

// ---------------- Kernel 2b: border-class corrections -----------------------
// corr[k*16 + cls] = sum over invalid taps (per cls bits) of popc(w[k,t])
// cls bits: 1 = x==0 (dx=-1 invalid), 2 = x==31, 4 = y==0, 8 = y==31
__global__ __launch_bounds__(256) void k_corr(const unsigned* __restrict__ wp,
                                              int* __restrict__ corr) {
  int idx = blockIdx.x * 256 + threadIdx.x;  // 0..4095 = k*16 + cls
  int k = idx >> 4, cls = idx & 15;
  int sum = 0;
  #pragma unroll
  for (int t = 0; t < 9; ++t) {
    int dy = t / 3 - 1, dx = t % 3 - 1;
    bool inv = (((cls & 1) && dx == -1) || ((cls & 2) && dx == 1) ||
                ((cls & 4) && dy == -1) || ((cls & 8) && dy == 1));
    if (inv) {
      const unsigned* w = wp + (size_t)(k * 9 + t) * 8;
      #pragma unroll
      for (int j = 0; j < 8; ++j) sum += __popc(w[j]);
    }
  }
  corr[idx] = sum;
}

// ------------- Kernel 3: binarize + bit-pack activations (NHW, C-bits) ------
__global__ __launch_bounds__(256) void k_packa(
    const float* __restrict__ x, const float* __restrict__ t,
    const unsigned* __restrict__ flip, unsigned* __restrict__ ap) {
  int n = blockIdx.y;
  int p0 = blockIdx.x * 64;          // 64 pixels per block
  int pix = threadIdx.x & 63;
  int q = threadIdx.x >> 6;          // channel quarter: c in [q*64, q*64+64)
  unsigned w0 = 0, w1 = 0;
  const float* xb = x + (size_t)n * (C * 1024) + p0 + pix;
  #pragma unroll
  for (int i = 0; i < 64; ++i) {
    int c = q * 64 + i;
    float tv = t[c];
    unsigned fl = flip[c];
    float v = xb[(size_t)c * 1024];
    unsigned bit = ((v > tv) ? 1u : 0u) ^ fl;
    if (i < 32) w0 |= bit << i;
    else        w1 |= bit << (i - 32);
  }
  uint2 st; st.x = w0; st.y = w1;
  *(uint2*)(ap + ((size_t)n * 1024 + p0 + pix) * 8 + q * 2) = st;
}

// ---------------- Kernel 4: XNOR-popcount conv ------------------------------
// grid (kchunk=16, ystrip=4, n=32), block 256 (4 waves; wave = 2 rows x 32 x)
// Mask-free: invalid taps read the zero page; border corrected via corr table.
__global__ __launch_bounds__(256) void k_conv(
    const unsigned* __restrict__ ap, const unsigned* __restrict__ wp,
    const int* __restrict__ corr, const unsigned* __restrict__ zp,
    float* __restrict__ out) {
  int n = blockIdx.z;
  int ystrip = blockIdx.y;
  int kc = blockIdx.x;               // 16 output channels per block
  int tid = threadIdx.x;
  int lane = tid & 63;
  int wave = tid >> 6;
  int y = ystrip * 8 + wave * 2 + (lane >> 5);
  int xx = lane & 31;

  int cls = (xx == 0 ? 1 : 0) | (xx == 31 ? 2 : 0) |
            (y == 0 ? 4 : 0) | (y == 31 ? 8 : 0);

  uint4 a0[9], a1[9];
  int nv = 0;
  const uint4* zp4 = (const uint4*)zp;
  #pragma unroll
  for (int t = 0; t < 9; ++t) {
    int dy = t / 3 - 1, dx = t % 3 - 1;
    int cy = y + dy, cx = xx + dx;
    bool valid = (cy >= 0) & (cy < 32) & (cx >= 0) & (cx < 32);
    nv += valid ? 1 : 0;
    const uint4* pa = valid
        ? (const uint4*)(ap + (((size_t)n * 32 + cy) * 32 + cx) * 8)
        : zp4;
    a0[t] = pa[0];
    a1[t] = pa[1];
  }
  int bias = nv << 8;                // 256 * nv

  float* ob = out + (size_t)n * (K * 1024) + (size_t)y * 32 + xx;
  for (int kk = 0; kk < 16; ++kk) {
    int k = kc * 16 + kk;
    const uint4* wq = (const uint4*)(wp + (size_t)k * 72);
    int s0 = 0, s1 = 0, s2 = 0, s3 = 0, s4 = 0, s5 = 0, s6 = 0, s7 = 0;
    #pragma unroll
    for (int t = 0; t < 9; ++t) {
      uint4 wa = wq[t * 2];
      uint4 wb = wq[t * 2 + 1];
      s0 += __popc(a0[t].x ^ wa.x);
      s1 += __popc(a0[t].y ^ wa.y);
      s2 += __popc(a0[t].z ^ wa.z);
      s3 += __popc(a0[t].w ^ wa.w);
      s4 += __popc(a1[t].x ^ wb.x);
      s5 += __popc(a1[t].y ^ wb.y);
      s6 += __popc(a1[t].z ^ wb.z);
      s7 += __popc(a1[t].w ^ wb.w);
    }
    int S = ((s0 + s1) + (s2 + s3)) + ((s4 + s5) + (s6 + s7));
    int tot = corr[(k << 4) + cls] - S;
    ob[(size_t)k * 1024] = (float)(bias + 2 * tot);
  }
}

extern "C" void kernel_launch(void* const* d_in, const int* in_sizes, int n_in,
                              void* d_out, int out_size, void* d_ws, size_t ws_size,
                              hipStream_t stream) {
  const float* x = (const float*)d_in[0];
  const float* gamma = (const float*)d_in[1];
  const float* beta = (const float*)d_in[2];
  const float* W = (const float*)d_in[3];
  float* out = (float*)d_out;

  char* ws = (char*)d_ws;
  float* t = (float*)ws;                         // 1 KB
  unsigned* flip = (unsigned*)(ws + 1024);       // 1 KB
  unsigned* wp = (unsigned*)(ws + 4096);         // 2304*8 u32 = 72 KB
  unsigned* zp = (unsigned*)(ws + 77824);        // 32 B zero page
  int* corr = (int*)(ws + 78336);                // 256*16 i32 = 16 KB
  double2* partials = (double2*)(ws + 98304);    // 256*8 double2 = 32 KB
  unsigned* ap = (unsigned*)(ws + 131072);       // 32768*8 u32 = 1 MB

  k_stats_part<<<dim3(8, 256), 256, 0, stream>>>(x, partials);
  k_stats_final<<<1, 256, 0, stream>>>(partials, gamma, beta, t, flip);
  k_packw<<<9, 256, 0, stream>>>(W, wp, zp);
  k_corr<<<16, 256, 0, stream>>>(wp, corr);
  k_packa<<<dim3(16, 32), 256, 0, stream>>>(x, t, flip, ap);
  k_conv<<<dim3(16, 4, 32), 256, 0, stream>>>(ap, wp, corr, zp, out);
}

// Round 3
// 67.978 us; speedup vs baseline: 1.7400x; 1.2714x over previous
//
#include <hip/hip_runtime.h>
#include <hip/hip_bf16.h>

// BinaryConv: BN(train) -> sign -> 3x3 conv with sign(W), via XNOR-popcount.
// x: (32,256,32,32) f32, gamma/beta: (256,), W: (256,256,3,3) f32 OIHW
// out: (32,256,32,32) f32

#define NIMG 32
#define C    256
#define K    256

// ---------------- Kernel 1: partial per-channel stats -----------------------
// grid (8 image-groups, 256 channels), block 256. f64 partials, fixed order.
__global__ __launch_bounds__(256) void k_stats_part(
    const float* __restrict__ x, double2* __restrict__ partials) {
  int grp = blockIdx.x;   // 0..7
  int c = blockIdx.y;     // 0..255
  int tid = threadIdx.x;
  double s = 0.0, sq = 0.0;
  #pragma unroll
  for (int ni = 0; ni < 4; ++ni) {
    int n = grp * 4 + ni;
    const float* p = x + (size_t)n * (C * 1024) + (size_t)c * 1024;
    float4 v = ((const float4*)p)[tid];
    s += (double)v.x + (double)v.y + (double)v.z + (double)v.w;
    sq += (double)v.x * v.x + (double)v.y * v.y
        + (double)v.z * v.z + (double)v.w * v.w;
  }
  for (int o = 32; o > 0; o >>= 1) {
    s += __shfl_down(s, o);
    sq += __shfl_down(sq, o);
  }
  __shared__ double ls[4], lq[4];
  if ((tid & 63) == 0) { ls[tid >> 6] = s; lq[tid >> 6] = sq; }
  __syncthreads();
  if (tid == 0) {
    double2 r;
    r.x = ls[0] + ls[1] + ls[2] + ls[3];
    r.y = lq[0] + lq[1] + lq[2] + lq[3];
    partials[c * 8 + grp] = r;
  }
}

// ------- Kernel 2: pack sign(W) via ballot + corr + zp + stats-final --------
// blocks 0..255: one output channel k each. block 256: fold stats -> t, flip.
__global__ __launch_bounds__(256) void k_packw_corr_final(
    const float* __restrict__ W, const double2* __restrict__ partials,
    const float* __restrict__ gamma, const float* __restrict__ beta,
    unsigned* __restrict__ wp, int* __restrict__ corr,
    unsigned* __restrict__ zp, float* __restrict__ t_out,
    unsigned* __restrict__ flip_out) {
  int bk = blockIdx.x;
  int tid = threadIdx.x;
  if (bk == 256) {                       // ---- stats final ----
    int c = tid;
    double S = 0.0, Q = 0.0;
    #pragma unroll
    for (int g = 0; g < 8; ++g) {        // fixed order -> deterministic
      double2 p = partials[c * 8 + g];
      S += p.x; Q += p.y;
    }
    const double N = 32768.0;
    double mean = S / N;
    double var = Q / N - mean * mean;
    double rs = 1.0 / sqrt(var + 1e-5);
    double g = (double)gamma[c];
    double b = (double)beta[c];
    float t;
    unsigned flip;
    if (g == 0.0) {
      t = (b > 0.0) ? -3.0e38f : 3.0e38f;
      flip = 0u;
    } else {
      t = (float)(mean - b / (rs * g));
      flip = (g < 0.0) ? 1u : 0u;
    }
    t_out[c] = t;
    flip_out[c] = flip;
    return;
  }
  // ---- pack one k ----
  int k = bk;
  __shared__ unsigned lw[72];
  float w[9];
  const float* src = W + (size_t)k * 2304 + (size_t)tid * 9;
  #pragma unroll
  for (int t = 0; t < 9; ++t) w[t] = src[t];
  int lane = tid & 63, wv = tid >> 6;
  #pragma unroll
  for (int t = 0; t < 9; ++t) {
    unsigned long long m = __ballot(w[t] > 0.0f);
    if (lane == 0) {
      lw[t * 8 + 2 * wv] = (unsigned)m;
      lw[t * 8 + 2 * wv + 1] = (unsigned)(m >> 32);
    }
  }
  __syncthreads();
  if (tid < 72) wp[(size_t)k * 72 + tid] = lw[tid];
  if (tid >= 128 && tid < 144) {         // corr for 16 border classes
    int cls = tid - 128;
    int sum = 0;
    #pragma unroll
    for (int t = 0; t < 9; ++t) {
      int dy = t / 3 - 1, dx = t % 3 - 1;
      bool inv = (((cls & 1) && dx == -1) || ((cls & 2) && dx == 1) ||
                  ((cls & 4) && dy == -1) || ((cls & 8) && dy == 1));
      if (inv) {
        #pragma unroll
        for (int j = 0; j < 8; ++j) sum += __popc(lw[t * 8 + j]);
      }
    }
    corr[k * 16 + cls] = sum;
  }
  if (bk == 0 && tid >= 192 && tid < 200) zp[tid - 192] = 0u;
}

// ------- Kernel 3: binarize + bit-pack activations (NHW, C-bits) ------------
__global__ __launch_bounds__(256) void k_packa(
    const float* __restrict__ x, const float* __restrict__ t,
    const unsigned* __restrict__ flip, unsigned* __restrict__ ap) {
  int n = blockIdx.y;
  int p0 = blockIdx.x * 64;          // 64 pixels per block
  int pix = threadIdx.x & 63;
  int q = threadIdx.x >> 6;          // channel quarter: c in [q*64, q*64+64)
  unsigned w0 = 0, w1 = 0;
  const float* xb = x + (size_t)n * (C * 1024) + p0 + pix;
  #pragma unroll
  for (int i = 0; i < 64; ++i) {
    int c = q * 64 + i;
    float tv = t[c];
    unsigned fl = flip[c];
    float v = xb[(size_t)c * 1024];
    unsigned bit = ((v > tv) ? 1u : 0u) ^ fl;
    if (i < 32) w0 |= bit << i;
    else        w1 |= bit << (i - 32);
  }
  uint2 st; st.x = w0; st.y = w1;
  *(uint2*)(ap + ((size_t)n * 1024 + p0 + pix) * 8 + q * 2) = st;
}

// ---------------- Kernel 4: XNOR-popcount conv ------------------------------
// grid (kchunk=16, ystrip=4, n=32), block 256 (4 waves; wave = 2 rows x 32 x)
// Weights + corr staged in LDS; inner loop = ds_read(imm offset) + xor/bcnt.
__global__ __launch_bounds__(256) void k_conv(
    const unsigned* __restrict__ ap, const unsigned* __restrict__ wp,
    const int* __restrict__ corr, const unsigned* __restrict__ zp,
    float* __restrict__ out) {
  __shared__ uint4 lw4[288];           // 16 k * 18 uint4 = 4608 B
  __shared__ int lcorr[256];           // 16 k * 16 cls
  int n = blockIdx.z;
  int ystrip = blockIdx.y;
  int kc = blockIdx.x;                 // 16 output channels per block
  int tid = threadIdx.x;

  {
    const uint4* srcw = (const uint4*)(wp + (size_t)kc * 16 * 72);
    lw4[tid] = srcw[tid & 255 ? tid : tid];  // placeholder avoided below
  }
  // (re-do staging cleanly)
  {
    const uint4* srcw = (const uint4*)(wp + (size_t)kc * 16 * 72);
    lw4[tid] = srcw[tid];
    if (tid < 32) lw4[256 + tid] = srcw[256 + tid];
    lcorr[tid] = corr[kc * 256 + tid];
  }

  int lane = tid & 63;
  int wave = tid >> 6;
  int y = ystrip * 8 + wave * 2 + (lane >> 5);
  int xx = lane & 31;
  int cls = (xx == 0 ? 1 : 0) | (xx == 31 ? 2 : 0) |
            (y == 0 ? 4 : 0) | (y == 31 ? 8 : 0);

  uint4 a0[9], a1[9];
  int nv = 0;
  const uint4* zp4 = (const uint4*)zp;
  #pragma unroll
  for (int t = 0; t < 9; ++t) {
    int dy = t / 3 - 1, dx = t % 3 - 1;
    int cy = y + dy, cx = xx + dx;
    bool valid = (cy >= 0) & (cy < 32) & (cx >= 0) & (cx < 32);
    nv += valid ? 1 : 0;
    const uint4* pa = valid
        ? (const uint4*)(ap + (((size_t)n * 32 + cy) * 32 + cx) * 8)
        : zp4;
    a0[t] = pa[0];
    a1[t] = pa[1];
  }
  int bias = nv << 8;                  // 256 * nv

  __syncthreads();

  float* ob = out + (size_t)n * (K * 1024) + (size_t)y * 32 + xx
            + (size_t)kc * 16 * 1024;
  for (int kk = 0; kk < 16; ++kk) {
    const uint4* wq = lw4 + kk * 18;
    int s0 = 0, s1 = 0, s2 = 0, s3 = 0, s4 = 0, s5 = 0, s6 = 0, s7 = 0;
    #pragma unroll
    for (int t = 0; t < 9; ++t) {
      uint4 wa = wq[t * 2];
      uint4 wb = wq[t * 2 + 1];
      s0 += __popc(a0[t].x ^ wa.x);
      s1 += __popc(a0[t].y ^ wa.y);
      s2 += __popc(a0[t].z ^ wa.z);
      s3 += __popc(a0[t].w ^ wa.w);
      s4 += __popc(a1[t].x ^ wb.x);
      s5 += __popc(a1[t].y ^ wb.y);
      s6 += __popc(a1[t].z ^ wb.z);
      s7 += __popc(a1[t].w ^ wb.w);
    }
    int S = ((s0 + s1) + (s2 + s3)) + ((s4 + s5) + (s6 + s7));
    int tot = lcorr[kk * 16 + cls] - S;
    ob[(size_t)kk * 1024] = (float)(bias + 2 * tot);
  }
}

extern "C" void kernel_launch(void* const* d_in, const int* in_sizes, int n_in,
                              void* d_out, int out_size, void* d_ws, size_t ws_size,
                              hipStream_t stream) {
  const float* x = (const float*)d_in[0];
  const float* gamma = (const float*)d_in[1];
  const float* beta = (const float*)d_in[2];
  const float* W = (const float*)d_in[3];
  float* out = (float*)d_out;

  char* ws = (char*)d_ws;
  float* t = (float*)ws;                         // 1 KB
  unsigned* flip = (unsigned*)(ws + 1024);       // 1 KB
  unsigned* wp = (unsigned*)(ws + 4096);         // 2304*8 u32 = 72 KB
  unsigned* zp = (unsigned*)(ws + 77824);        // 32 B zero page
  int* corr = (int*)(ws + 78336);                // 256*16 i32 = 16 KB
  double2* partials = (double2*)(ws + 98304);    // 256*8 double2 = 32 KB
  unsigned* ap = (unsigned*)(ws + 131072);       // 32768*8 u32 = 1 MB

  k_stats_part<<<dim3(8, 256), 256, 0, stream>>>(x, partials);
  k_packw_corr_final<<<257, 256, 0, stream>>>(W, partials, gamma, beta,
                                              wp, corr, zp, t, flip);
  k_packa<<<dim3(16, 32), 256, 0, stream>>>(x, t, flip, ap);
  k_conv<<<dim3(16, 4, 32), 256, 0, stream>>>(ap, wp, corr, zp, out);
}